// Round 3
// baseline (350.205 us; speedup 1.0000x reference)
//
#include <hip/hip_runtime.h>
#include <hip/hip_bf16.h>
#include <stdint.h>

#define BATCH 8192
#define DDIM 1024
#define NCLS 8
#define EPSN 1e-8f

typedef __bf16 bf16x8 __attribute__((ext_vector_type(8)));
typedef float f32x4 __attribute__((ext_vector_type(4)));

// ws layout: [0..63] float accums (0=ce_sum, 1=center_sum, 2=soft_sum)
// offset 256 bytes: fn bf16 [8192][1024]  (16 MiB)

__device__ __forceinline__ unsigned short f2bf(float x) {
    unsigned int u = __builtin_bit_cast(unsigned int, x);
    unsigned int r = (u + 0x7fffu + ((u >> 16) & 1u)) >> 16;
    return (unsigned short)r;
}

__device__ __forceinline__ void gload16(const void* g, void* l) {
    __builtin_amdgcn_global_load_lds(
        (const __attribute__((address_space(1))) void*)g,
        (__attribute__((address_space(3))) void*)l, 16, 0, 0);
}

// ---------------- prep: row norms -> fn (bf16), center loss partials ----------
__global__ __launch_bounds__(256) void prep_kernel(
    const float* __restrict__ feat, const int* __restrict__ labels,
    const float* __restrict__ centers, float* __restrict__ accums,
    unsigned short* __restrict__ fn)
{
    int wave = threadIdx.x >> 6;
    int lane = threadIdx.x & 63;
    int row  = blockIdx.x * 4 + wave;
    const float* frow = feat + (size_t)row * DDIM;
    int lab = labels[row];
    const float* crow = centers + (size_t)lab * DDIM;

    float4 f[4];
    float ss = 0.f, cp = 0.f;
#pragma unroll
    for (int q = 0; q < 4; q++) {
        f[q] = *(const float4*)(frow + q * 256 + lane * 4);
        float4 cv = *(const float4*)(crow + q * 256 + lane * 4);
        ss += f[q].x * f[q].x + f[q].y * f[q].y + f[q].z * f[q].z + f[q].w * f[q].w;
        float dx = f[q].x - cv.x, dy = f[q].y - cv.y, dz = f[q].z - cv.z, dw = f[q].w - cv.w;
        cp += dx * dx + dy * dy + dz * dz + dw * dw;
    }
#pragma unroll
    for (int o = 32; o > 0; o >>= 1) {
        ss += __shfl_xor(ss, o);
        cp += __shfl_xor(cp, o);
    }
    float scale = 1.0f / fmaxf(sqrtf(ss), EPSN);
#pragma unroll
    for (int q = 0; q < 4; q++) {
        ushort4 o4;
        o4.x = f2bf(f[q].x * scale);
        o4.y = f2bf(f[q].y * scale);
        o4.z = f2bf(f[q].z * scale);
        o4.w = f2bf(f[q].w * scale);
        *(ushort4*)(fn + (size_t)row * DDIM + q * 256 + lane * 4) = o4;
    }
    if (lane == 0) atomicAdd(&accums[1], cp);
}

// ---------------- cross entropy ----------------
__global__ __launch_bounds__(256) void ce_kernel(
    const float* __restrict__ logits, const int* __restrict__ labels,
    float* __restrict__ accums)
{
    int i = blockIdx.x * 256 + threadIdx.x;
    float4 a = *(const float4*)(logits + (size_t)i * 8);
    float4 b = *(const float4*)(logits + (size_t)i * 8 + 4);
    float lv[8] = {a.x, a.y, a.z, a.w, b.x, b.y, b.z, b.w};
    int lab = labels[i];
    float m = lv[0];
#pragma unroll
    for (int k = 1; k < 8; k++) m = fmaxf(m, lv[k]);
    float s = 0.f, tgt = 0.f;
#pragma unroll
    for (int k = 0; k < 8; k++) {
        s += __expf(lv[k] - m);
        tgt += (k == lab) ? lv[k] : 0.f;
    }
    float ce = (m + __logf(s)) - tgt;
#pragma unroll
    for (int o = 32; o > 0; o >>= 1) ce += __shfl_xor(ce, o);
    if ((threadIdx.x & 63) == 0) atomicAdd(&accums[0], ce);
}

// ---------------- soft-cosine: fn @ fn^T with weighted relu epilogue ----------
#define BM 128
#define BK 32
#define NT (DDIM / BK)

__global__ __launch_bounds__(256) void soft_kernel(
    const unsigned short* __restrict__ fn, const int* __restrict__ labels,
    const float* __restrict__ sim, float* __restrict__ accums)
{
    int tc = blockIdx.x, tr = blockIdx.y;
    if (tr > tc) return;  // upper triangle only; off-diag weighted x2 via S[a][b]+S[b][a]

    __shared__ unsigned short Asub[2][BM * BK];
    __shared__ unsigned short Bsub[2][BM * BK];
    __shared__ int lrow[BM], lcol[BM];
    __shared__ float Ssm[64];
    __shared__ float red[4];

    int tid = threadIdx.x;
    if (tid < 64) Ssm[tid] = sim[tid];
    if (tid < 128) lrow[tid] = labels[tr * BM + tid];
    else           lcol[tid - 128] = labels[tc * BM + (tid - 128)];

    const unsigned short* Abase = fn + (size_t)tr * BM * DDIM;
    const unsigned short* Bbase = fn + (size_t)tc * BM * DDIM;
    int srow  = tid >> 2;        // 0..63
    int selem = (tid & 3) * 8;   // bf16 element offset in k

    auto STAGE = [&](int buf, int t) {
#pragma unroll
        for (int q = 0; q < 2; q++) {
            int r = q * 64 + srow;
            gload16(Abase + (size_t)r * DDIM + t * BK + selem, &Asub[buf][r * BK + selem]);
            gload16(Bbase + (size_t)r * DDIM + t * BK + selem, &Bsub[buf][r * BK + selem]);
        }
    };

    int lane   = tid & 63;
    int w      = tid >> 6;
    int wr     = w >> 1, wc = w & 1;  // 2x2 wave grid, 64x64 per wave
    int lr16   = lane & 15;
    int kgrp   = lane >> 4;

    f32x4 acc[4][4] = {};

    auto COMPUTE = [&](int buf) {
        bf16x8 af[4], bfm[4];
#pragma unroll
        for (int m = 0; m < 4; m++) {
            int r = wr * 64 + m * 16 + lr16;
            af[m] = *(const bf16x8*)&Asub[buf][r * BK + kgrp * 8];
        }
#pragma unroll
        for (int n = 0; n < 4; n++) {
            int c = wc * 64 + n * 16 + lr16;
            bfm[n] = *(const bf16x8*)&Bsub[buf][c * BK + kgrp * 8];
        }
#pragma unroll
        for (int m = 0; m < 4; m++)
#pragma unroll
            for (int n = 0; n < 4; n++)
                acc[m][n] = __builtin_amdgcn_mfma_f32_16x16x32_bf16(af[m], bfm[n], acc[m][n], 0, 0, 0);
    };

    STAGE(0, 0);
    __syncthreads();
    int cur = 0;
    for (int t = 0; t < NT - 1; t++) {
        STAGE(cur ^ 1, t + 1);
        COMPUTE(cur);
        __syncthreads();
        cur ^= 1;
    }
    COMPUTE(cur);

    // epilogue: w_ij * relu(1 - cos), mask diagonal, doubled weights off-diag tiles
    float local = 0.f;
    bool diag = (tr == tc);
#pragma unroll
    for (int m = 0; m < 4; m++) {
        int rbase = wr * 64 + m * 16 + kgrp * 4;
#pragma unroll
        for (int n = 0; n < 4; n++) {
            int c  = wc * 64 + n * 16 + lr16;
            int lb = lcol[c];
#pragma unroll
            for (int rg = 0; rg < 4; rg++) {
                int r  = rbase + rg;
                int la = lrow[r];
                float fv = fmaxf(1.0f - acc[m][n][rg], 0.0f);
                float wgt;
                if (!diag) wgt = Ssm[la * 8 + lb] + Ssm[lb * 8 + la];
                else       wgt = (r != c) ? Ssm[la * 8 + lb] : 0.0f;
                local += wgt * fv;
            }
        }
    }
#pragma unroll
    for (int o = 32; o > 0; o >>= 1) local += __shfl_xor(local, o);
    if (lane == 0) red[w] = local;
    __syncthreads();
    if (tid == 0) atomicAdd(&accums[2], red[0] + red[1] + red[2] + red[3]);
}

// ---------------- finalize ----------------
__global__ void finalize_kernel(const float* __restrict__ accums, float* __restrict__ out)
{
    float ce = accums[0] / (float)BATCH;
    float cl = accums[1] / (2.0f * (float)BATCH);
    float sc = accums[2] / ((float)BATCH * (float)(BATCH - 1));
    out[0] = ce + cl + sc;
}

extern "C" void kernel_launch(void* const* d_in, const int* in_sizes, int n_in,
                              void* d_out, int out_size, void* d_ws, size_t ws_size,
                              hipStream_t stream)
{
    const float* feat    = (const float*)d_in[0];
    const int*   labels  = (const int*)d_in[1];
    const float* logits  = (const float*)d_in[2];
    const float* sim     = (const float*)d_in[3];
    const float* centers = (const float*)d_in[4];
    float* out = (float*)d_out;

    float* accums = (float*)d_ws;
    unsigned short* fn = (unsigned short*)((char*)d_ws + 256);

    hipMemsetAsync(d_ws, 0, 256, stream);
    prep_kernel<<<BATCH / 4, 256, 0, stream>>>(feat, labels, centers, accums, fn);
    ce_kernel<<<BATCH / 256, 256, 0, stream>>>(logits, labels, accums);
    dim3 g(BATCH / BM, BATCH / BM);
    soft_kernel<<<g, 256, 0, stream>>>(fn, labels, sim, accums);
    finalize_kernel<<<1, 1, 0, stream>>>(accums, out);
}

// Round 4
// 243.437 us; speedup vs baseline: 1.4386x; 1.4386x over previous
//
#include <hip/hip_runtime.h>
#include <hip/hip_bf16.h>
#include <stdint.h>

#define BATCH 8192
#define DDIM 1024
#define EPSN 1e-8f

typedef __bf16 bf16x8 __attribute__((ext_vector_type(8)));
typedef float f32x4 __attribute__((ext_vector_type(4)));

// ws layout: [0..63] float accums (0=ce_sum, 1=center_sum, 2=soft_sum)
// offset 256 bytes: fn bf16 [8192][1024]  (16 MiB)

__device__ __forceinline__ unsigned short f2bf(float x) {
    unsigned int u = __builtin_bit_cast(unsigned int, x);
    unsigned int r = (u + 0x7fffu + ((u >> 16) & 1u)) >> 16;
    return (unsigned short)r;
}

__device__ __forceinline__ void gload16(const void* g, void* l) {
    __builtin_amdgcn_global_load_lds(
        (const __attribute__((address_space(1))) void*)g,
        (__attribute__((address_space(3))) void*)l, 16, 0, 0);
}

// ---------------- prep: row norms -> fn (bf16), center loss partials ----------
__global__ __launch_bounds__(256) void prep_kernel(
    const float* __restrict__ feat, const int* __restrict__ labels,
    const float* __restrict__ centers, float* __restrict__ accums,
    unsigned short* __restrict__ fn)
{
    __shared__ float pr[4];
    int wave = threadIdx.x >> 6;
    int lane = threadIdx.x & 63;
    int row  = blockIdx.x * 4 + wave;
    const float* frow = feat + (size_t)row * DDIM;
    int lab = labels[row];
    const float* crow = centers + (size_t)lab * DDIM;

    float4 f[4];
    float ss = 0.f, cp = 0.f;
#pragma unroll
    for (int q = 0; q < 4; q++) {
        f[q] = *(const float4*)(frow + q * 256 + lane * 4);
        float4 cv = *(const float4*)(crow + q * 256 + lane * 4);
        ss += f[q].x * f[q].x + f[q].y * f[q].y + f[q].z * f[q].z + f[q].w * f[q].w;
        float dx = f[q].x - cv.x, dy = f[q].y - cv.y, dz = f[q].z - cv.z, dw = f[q].w - cv.w;
        cp += dx * dx + dy * dy + dz * dz + dw * dw;
    }
#pragma unroll
    for (int o = 32; o > 0; o >>= 1) {
        ss += __shfl_xor(ss, o);
        cp += __shfl_xor(cp, o);
    }
    float scale = 1.0f / fmaxf(sqrtf(ss), EPSN);
#pragma unroll
    for (int q = 0; q < 4; q++) {
        ushort4 o4;
        o4.x = f2bf(f[q].x * scale);
        o4.y = f2bf(f[q].y * scale);
        o4.z = f2bf(f[q].z * scale);
        o4.w = f2bf(f[q].w * scale);
        *(ushort4*)(fn + (size_t)row * DDIM + q * 256 + lane * 4) = o4;
    }
    if (lane == 0) pr[wave] = cp;
    __syncthreads();
    if (threadIdx.x == 0) atomicAdd(&accums[1], pr[0] + pr[1] + pr[2] + pr[3]);
}

// ---------------- cross entropy ----------------
__global__ __launch_bounds__(256) void ce_kernel(
    const float* __restrict__ logits, const int* __restrict__ labels,
    float* __restrict__ accums)
{
    int i = blockIdx.x * 256 + threadIdx.x;
    float4 a = *(const float4*)(logits + (size_t)i * 8);
    float4 b = *(const float4*)(logits + (size_t)i * 8 + 4);
    float lv[8] = {a.x, a.y, a.z, a.w, b.x, b.y, b.z, b.w};
    int lab = labels[i];
    float m = lv[0];
#pragma unroll
    for (int k = 1; k < 8; k++) m = fmaxf(m, lv[k]);
    float s = 0.f, tgt = 0.f;
#pragma unroll
    for (int k = 0; k < 8; k++) {
        s += __expf(lv[k] - m);
        tgt += (k == lab) ? lv[k] : 0.f;
    }
    float ce = (m + __logf(s)) - tgt;
#pragma unroll
    for (int o = 32; o > 0; o >>= 1) ce += __shfl_xor(ce, o);
    if ((threadIdx.x & 63) == 0) atomicAdd(&accums[0], ce);
}

// ---------------- soft-cosine: 256^2 tile, 8-phase counted-vmcnt schedule ----
// Regions per K-tile(BK=64): s&3 = 0:Akk0 1:Bkk0 2:Akk1 3:Bkk1, each [256][32] bf16 (16KB).
// Stream s = 4*kt + r; phase q = 4*kt + p consumes regions <= q+1; issues region q+6.
// LDS slot ring = 2 bufs x 4 regions (period 8); uniform vmcnt(8) in main loop.
// LDS XOR-swizzle: slot(row, chunk16) holds logical chunk16 ^ ((row>>1)&3)  (2-way = free).

__global__ __launch_bounds__(512, 2) void soft_kernel(
    const unsigned short* __restrict__ fn, const int* __restrict__ labels,
    const float* __restrict__ sim, float* __restrict__ accums)
{
    __shared__ __align__(16) unsigned short tiles[2][4][256][32];  // 128 KiB
    __shared__ int lrow[256], lcol[256];
    __shared__ float Ssm[64], W2s[64];

    int tid  = threadIdx.x;
    int lane = tid & 63;
    int w    = tid >> 6;
    int wr   = w >> 2, wc = w & 3;      // 2x4 wave grid; wave owns 128x64
    int lr16 = lane & 15;
    int kgrp = lane >> 4;

    // triangle decode with bijective XCD swizzle (528 = 8*66)
    int b0i = blockIdx.x;
    int swz = (b0i & 7) * 66 + (b0i >> 3);
    int tr = 0, rem = swz;
    while (rem >= 32 - tr) { rem -= 32 - tr; tr++; }
    int tc = tr + rem;
    bool diag = (tr == tc);

    const unsigned short* Abase = fn + (size_t)tr * 256 * DDIM;
    const unsigned short* Bbase = fn + (size_t)tc * 256 * DDIM;

    // staging geometry: region = 1024 slots of 16B; thread covers idx = {tid, 512+tid}
    int myrow  = tid >> 2;                     // 0..127 (l=1 adds 128)
    int mychk  = tid & 3;
    int mycol8 = mychk ^ ((myrow >> 1) & 3);   // pre-swizzled global source
    int goff0  = myrow * DDIM + mycol8 * 8;

    auto ISSUE = [&](int s) {
        int kt_s = s >> 2, r = s & 3, kk = r >> 1;
        const unsigned short* gb = (r & 1) ? Bbase : Abase;
        const unsigned short* g0 = gb + goff0 + kt_s * 64 + kk * 32;
        unsigned short* l0 = &tiles[kt_s & 1][r][0][0] + tid * 8;
        gload16(g0, l0);
        gload16(g0 + 128 * DDIM, l0 + 512 * 8);
    };

    // prologue: stage regions 0..5, load labels/weights, full drain once
#pragma unroll
    for (int s = 0; s < 6; s++) ISSUE(s);
    if (tid < 256) {
        lrow[tid] = labels[tr * 256 + tid];
        lcol[tid] = labels[tc * 256 + tid];
    }
    if (tid < 64) {
        float sv = sim[tid];
        Ssm[tid] = sv;
        W2s[tid] = sv + sim[(tid & 7) * 8 + (tid >> 3)];
    }
    __syncthreads();

    f32x4 acc[8][4] = {};
    bf16x8 a[8];

#define PHASE(BUF, KK, NP, S, VMSTR) { \
    const unsigned short* Ar = &tiles[BUF][(KK)*2][0][0]; \
    const unsigned short* Br = &tiles[BUF][(KK)*2+1][0][0]; \
    bf16x8 b0, b1; \
    if ((NP) == 0) { \
        _Pragma("unroll") \
        for (int m = 0; m < 8; m++) { \
            int row = wr * 128 + m * 16 + lr16; \
            a[m] = *(const bf16x8*)((const char*)Ar + row * 64 + ((kgrp ^ ((row >> 1) & 3)) * 16)); \
        } \
    } \
    { int c0 = wc * 64 + ((NP)*2) * 16 + lr16; \
      b0 = *(const bf16x8*)((const char*)Br + c0 * 64 + ((kgrp ^ ((c0 >> 1) & 3)) * 16)); } \
    { int c1 = wc * 64 + ((NP)*2+1) * 16 + lr16; \
      b1 = *(const bf16x8*)((const char*)Br + c1 * 64 + ((kgrp ^ ((c1 >> 1) & 3)) * 16)); } \
    { int s_ = (S); if (s_ <= 63) ISSUE(s_); } \
    asm volatile("s_waitcnt vmcnt(" VMSTR ")" ::: "memory"); \
    __builtin_amdgcn_s_barrier(); \
    __builtin_amdgcn_sched_barrier(0); \
    asm volatile("s_waitcnt lgkmcnt(0)" ::: "memory"); \
    __builtin_amdgcn_sched_barrier(0); \
    __builtin_amdgcn_s_setprio(1); \
    _Pragma("unroll") \
    for (int m = 0; m < 8; m++) { \
        acc[m][(NP)*2]   = __builtin_amdgcn_mfma_f32_16x16x32_bf16(a[m], b0, acc[m][(NP)*2], 0, 0, 0); \
        acc[m][(NP)*2+1] = __builtin_amdgcn_mfma_f32_16x16x32_bf16(a[m], b1, acc[m][(NP)*2+1], 0, 0, 0); \
    } \
    __builtin_amdgcn_s_setprio(0); \
    __builtin_amdgcn_sched_barrier(0); \
    __builtin_amdgcn_s_barrier(); \
    __builtin_amdgcn_sched_barrier(0); \
}

#define KTILE(BUF, QB, V1, V2, V3, V4) \
    PHASE(BUF, 0, 0, (QB) + 6, V1) \
    PHASE(BUF, 0, 1, (QB) + 7, V2) \
    PHASE(BUF, 1, 0, (QB) + 8, V3) \
    PHASE(BUF, 1, 1, (QB) + 9, V4)

    int q = 0;
    for (int i = 0; i < 7; i++) {          // kt = 0..13
        KTILE(0, q, "8", "8", "8", "8") q += 4;
        KTILE(1, q, "8", "8", "8", "8") q += 4;
    }
    KTILE(0, 56, "8", "8", "6", "4")        // kt = 14
    KTILE(1, 60, "2", "0", "0", "0")        // kt = 15

#undef KTILE
#undef PHASE

    // epilogue: sum w_ij * relu(1 - cos) over this 256x256 tile
    float local = 0.f;
    int lb[4], cc[4];
#pragma unroll
    for (int n = 0; n < 4; n++) { cc[n] = wc * 64 + n * 16 + lr16; lb[n] = lcol[cc[n]]; }
#pragma unroll
    for (int m = 0; m < 8; m++) {
#pragma unroll
        for (int rg = 0; rg < 4; rg++) {
            int r = wr * 128 + m * 16 + kgrp * 4 + rg;
            int la8 = lrow[r] * 8;
#pragma unroll
            for (int n = 0; n < 4; n++) {
                float v = fmaxf(1.0f - acc[m][n][rg], 0.f);
                float wgt = diag ? ((r == cc[n]) ? 0.f : Ssm[la8 + lb[n]])
                                 : W2s[la8 + lb[n]];
                local += wgt * v;
            }
        }
    }
#pragma unroll
    for (int o = 32; o > 0; o >>= 1) local += __shfl_xor(local, o);
    if (lane == 0) atomicAdd(&accums[2], local);
}

// ---------------- finalize ----------------
__global__ void finalize_kernel(const float* __restrict__ accums, float* __restrict__ out)
{
    float ce = accums[0] / (float)BATCH;
    float cl = accums[1] / (2.0f * (float)BATCH);
    float sc = accums[2] / ((float)BATCH * (float)(BATCH - 1));
    out[0] = ce + cl + sc;
}

extern "C" void kernel_launch(void* const* d_in, const int* in_sizes, int n_in,
                              void* d_out, int out_size, void* d_ws, size_t ws_size,
                              hipStream_t stream)
{
    const float* feat    = (const float*)d_in[0];
    const int*   labels  = (const int*)d_in[1];
    const float* logits  = (const float*)d_in[2];
    const float* sim     = (const float*)d_in[3];
    const float* centers = (const float*)d_in[4];
    float* out = (float*)d_out;

    float* accums = (float*)d_ws;
    unsigned short* fn = (unsigned short*)((char*)d_ws + 256);

    hipMemsetAsync(d_ws, 0, 256, stream);
    prep_kernel<<<BATCH / 4, 256, 0, stream>>>(feat, labels, centers, accums, fn);
    ce_kernel<<<BATCH / 256, 256, 0, stream>>>(logits, labels, accums);
    soft_kernel<<<528, 512, 0, stream>>>(fn, labels, sim, accums);
    finalize_kernel<<<1, 1, 0, stream>>>(accums, out);
}

// Round 6
// 232.011 us; speedup vs baseline: 1.5094x; 1.0492x over previous
//
#include <hip/hip_runtime.h>
#include <hip/hip_bf16.h>
#include <stdint.h>

#define BATCH 8192
#define DDIM 1024
#define EPSN 1e-8f

typedef __bf16 bf16x8 __attribute__((ext_vector_type(8)));
typedef float f32x4 __attribute__((ext_vector_type(4)));

// ws layout: [0..63] float accums (0=ce_sum, 1=center_sum, 2=soft_sum)
// offset 256 bytes: fn bf16 [8192][1024]  (16 MiB)

__device__ __forceinline__ unsigned short f2bf(float x) {
    unsigned int u = __builtin_bit_cast(unsigned int, x);
    unsigned int r = (u + 0x7fffu + ((u >> 16) & 1u)) >> 16;
    return (unsigned short)r;
}

__device__ __forceinline__ void gload16(const void* g, void* l) {
    __builtin_amdgcn_global_load_lds(
        (const __attribute__((address_space(1))) void*)g,
        (__attribute__((address_space(3))) void*)l, 16, 0, 0);
}

// ---------------- prep: row norms -> fn (bf16), center loss partials ----------
__global__ __launch_bounds__(256) void prep_kernel(
    const float* __restrict__ feat, const int* __restrict__ labels,
    const float* __restrict__ centers, float* __restrict__ accums,
    unsigned short* __restrict__ fn)
{
    __shared__ float pr[4];
    int wave = threadIdx.x >> 6;
    int lane = threadIdx.x & 63;
    int row  = blockIdx.x * 4 + wave;
    const float* frow = feat + (size_t)row * DDIM;
    int lab = labels[row];
    const float* crow = centers + (size_t)lab * DDIM;

    float4 f[4];
    float ss = 0.f, cp = 0.f;
#pragma unroll
    for (int q = 0; q < 4; q++) {
        f[q] = *(const float4*)(frow + q * 256 + lane * 4);
        float4 cv = *(const float4*)(crow + q * 256 + lane * 4);
        ss += f[q].x * f[q].x + f[q].y * f[q].y + f[q].z * f[q].z + f[q].w * f[q].w;
        float dx = f[q].x - cv.x, dy = f[q].y - cv.y, dz = f[q].z - cv.z, dw = f[q].w - cv.w;
        cp += dx * dx + dy * dy + dz * dz + dw * dw;
    }
#pragma unroll
    for (int o = 32; o > 0; o >>= 1) {
        ss += __shfl_xor(ss, o);
        cp += __shfl_xor(cp, o);
    }
    float scale = 1.0f / fmaxf(sqrtf(ss), EPSN);
#pragma unroll
    for (int q = 0; q < 4; q++) {
        ushort4 o4;
        o4.x = f2bf(f[q].x * scale);
        o4.y = f2bf(f[q].y * scale);
        o4.z = f2bf(f[q].z * scale);
        o4.w = f2bf(f[q].w * scale);
        *(ushort4*)(fn + (size_t)row * DDIM + q * 256 + lane * 4) = o4;
    }
    if (lane == 0) pr[wave] = cp;
    __syncthreads();
    if (threadIdx.x == 0) atomicAdd(&accums[1], pr[0] + pr[1] + pr[2] + pr[3]);
}

// ---------------- cross entropy ----------------
__global__ __launch_bounds__(256) void ce_kernel(
    const float* __restrict__ logits, const int* __restrict__ labels,
    float* __restrict__ accums)
{
    int i = blockIdx.x * 256 + threadIdx.x;
    float4 a = *(const float4*)(logits + (size_t)i * 8);
    float4 b = *(const float4*)(logits + (size_t)i * 8 + 4);
    float lv[8] = {a.x, a.y, a.z, a.w, b.x, b.y, b.z, b.w};
    int lab = labels[i];
    float m = lv[0];
#pragma unroll
    for (int k = 1; k < 8; k++) m = fmaxf(m, lv[k]);
    float s = 0.f, tgt = 0.f;
#pragma unroll
    for (int k = 0; k < 8; k++) {
        s += __expf(lv[k] - m);
        tgt += (k == lab) ? lv[k] : 0.f;
    }
    float ce = (m + __logf(s)) - tgt;
#pragma unroll
    for (int o = 32; o > 0; o >>= 1) ce += __shfl_xor(ce, o);
    if ((threadIdx.x & 63) == 0) atomicAdd(&accums[0], ce);
}

// ---------------- soft-cosine: 256^2 tile, de-pinned 8-phase schedule --------
// Regions: s&3 = 0:Akk0 1:Bkk0 2:Akk1 3:Bkk1, each [256][32] bf16 (16KB, 2 gloads/wave).
// Phase q consumes region pair {q&~1, q|1}; ISSUE(q+5) (ring 8 slots, distance 5).
// Single barrier/phase. vmcnt(6) on ODD phases only: guarantees regions <= q+2
// landed (next even phase's pair). Distance-5 slot reuse: write at phase q lands
// into region q-3's slot; its readers finished >= 2 barriers earlier -> race-free.
// LDS XOR-swizzle: chunk16 ^ ((row>>1)&3) on both staging source and ds_read.

__global__ __launch_bounds__(512, 2) void soft_kernel(
    const unsigned short* __restrict__ fn, const int* __restrict__ labels,
    const float* __restrict__ sim, float* __restrict__ accums)
{
    __shared__ __align__(16) unsigned short tiles[2][4][256][32];  // 128 KiB
    __shared__ int lrow[256], lcol[256];
    __shared__ float Ssm[64], W2s[64];

    int tid  = threadIdx.x;
    int lane = tid & 63;
    int w    = tid >> 6;
    int wr   = w >> 2, wc = w & 3;      // 2x4 wave grid; wave owns 128x64
    int lr16 = lane & 15;
    int kgrp = lane >> 4;

    // triangle decode with bijective XCD swizzle (528 = 8*66)
    int b0i = blockIdx.x;
    int swz = (b0i & 7) * 66 + (b0i >> 3);
    int tr = 0, rem = swz;
    while (rem >= 32 - tr) { rem -= 32 - tr; tr++; }
    int tc = tr + rem;
    bool diag = (tr == tc);

    const unsigned short* Abase = fn + (size_t)tr * 256 * DDIM;
    const unsigned short* Bbase = fn + (size_t)tc * 256 * DDIM;

    // staging geometry: region = 1024 slots of 16B; thread covers idx = {tid, 512+tid}
    int myrow  = tid >> 2;                     // 0..127 (second load adds 128)
    int mychk  = tid & 3;
    int mycol8 = mychk ^ ((myrow >> 1) & 3);   // pre-swizzled global source
    int goff0  = myrow * DDIM + mycol8 * 8;

    auto ISSUE = [&](int s) {
        int kt_s = s >> 2, r = s & 3, kk = r >> 1;
        const unsigned short* gb = (r & 1) ? Bbase : Abase;
        const unsigned short* g0 = gb + goff0 + kt_s * 64 + kk * 32;
        unsigned short* l0 = &tiles[kt_s & 1][r][0][0] + tid * 8;
        gload16(g0, l0);
        gload16(g0 + 128 * DDIM, l0 + 512 * 8);
    };

    // prologue: stage regions 0..4 (10 loads/wave), labels/weights, then wait
    // until regions 0,1 landed (vmcnt 10-4=6) + lds writes visible.
#pragma unroll
    for (int s = 0; s < 5; s++) ISSUE(s);
    if (tid < 256) {
        lrow[tid] = labels[tr * 256 + tid];
        lcol[tid] = labels[tc * 256 + tid];
    }
    if (tid < 64) {
        float sv = sim[tid];
        Ssm[tid] = sv;
        W2s[tid] = sv + sim[(tid & 7) * 8 + (tid >> 3)];
    }
    asm volatile("s_waitcnt vmcnt(6) lgkmcnt(0)" ::: "memory");
    __builtin_amdgcn_s_barrier();
    asm volatile("" ::: "memory");

    f32x4 acc[8][4] = {};
    bf16x8 a[8];

#define VMW(N) asm volatile("s_waitcnt vmcnt(" #N ")" ::: "memory");
#define NOVM

#define PHASE(BUF, KK, NP, S, WAIT) { \
    if ((S) <= 63) ISSUE(S); \
    const unsigned short* Ar = &tiles[BUF][(KK)*2][0][0]; \
    const unsigned short* Br = &tiles[BUF][(KK)*2+1][0][0]; \
    bf16x8 b0, b1; \
    { int c0 = wc * 64 + ((NP)*2) * 16 + lr16; \
      b0 = *(const bf16x8*)((const char*)Br + c0 * 64 + ((kgrp ^ ((c0 >> 1) & 3)) * 16)); } \
    { int c1 = wc * 64 + ((NP)*2+1) * 16 + lr16; \
      b1 = *(const bf16x8*)((const char*)Br + c1 * 64 + ((kgrp ^ ((c1 >> 1) & 3)) * 16)); } \
    if ((NP) == 0) { \
        _Pragma("unroll") \
        for (int m = 0; m < 8; m++) { \
            int row = wr * 128 + m * 16 + lr16; \
            a[m] = *(const bf16x8*)((const char*)Ar + row * 64 + ((kgrp ^ ((row >> 1) & 3)) * 16)); \
        } \
    } \
    WAIT \
    __builtin_amdgcn_s_barrier(); \
    asm volatile("" ::: "memory"); \
    __builtin_amdgcn_s_setprio(1); \
    _Pragma("unroll") \
    for (int m = 0; m < 8; m++) { \
        acc[m][(NP)*2]   = __builtin_amdgcn_mfma_f32_16x16x32_bf16(a[m], b0, acc[m][(NP)*2], 0, 0, 0); \
        acc[m][(NP)*2+1] = __builtin_amdgcn_mfma_f32_16x16x32_bf16(a[m], b1, acc[m][(NP)*2+1], 0, 0, 0); \
    } \
    __builtin_amdgcn_s_setprio(0); \
}

#define KTILE(BUF, QB, W1, W3) \
    PHASE(BUF, 0, 0, (QB) + 5, NOVM) \
    PHASE(BUF, 0, 1, (QB) + 6, W1) \
    PHASE(BUF, 1, 0, (QB) + 7, NOVM) \
    PHASE(BUF, 1, 1, (QB) + 8, W3)

    int q = 0;
    for (int i = 0; i < 7; i++) {          // kt = 0..13
        KTILE(0, q, VMW(6), VMW(6)) q += 4;
        KTILE(1, q, VMW(6), VMW(6)) q += 4;
    }
    KTILE(0, 56, VMW(6), VMW(4))            // kt = 14 (phases 56-59)
    KTILE(1, 60, VMW(0), NOVM)              // kt = 15 (phases 60-63)

#undef KTILE
#undef PHASE
#undef VMW
#undef NOVM

    // epilogue: sum w_ij * relu(1 - cos) over this 256x256 tile
    float local = 0.f;
    int lb[4], cc[4];
#pragma unroll
    for (int n = 0; n < 4; n++) { cc[n] = wc * 64 + n * 16 + lr16; lb[n] = lcol[cc[n]]; }
#pragma unroll
    for (int m = 0; m < 8; m++) {
#pragma unroll
        for (int rg = 0; rg < 4; rg++) {
            int r = wr * 128 + m * 16 + kgrp * 4 + rg;
            int la8 = lrow[r] * 8;
#pragma unroll
            for (int n = 0; n < 4; n++) {
                float v = fmaxf(1.0f - acc[m][n][rg], 0.f);
                float wgt = diag ? ((r == cc[n]) ? 0.f : Ssm[la8 + lb[n]])
                                 : W2s[la8 + lb[n]];
                local += wgt * v;
            }
        }
    }
#pragma unroll
    for (int o = 32; o > 0; o >>= 1) local += __shfl_xor(local, o);
    if (lane == 0) atomicAdd(&accums[2], local);
}

// ---------------- finalize ----------------
__global__ void finalize_kernel(const float* __restrict__ accums, float* __restrict__ out)
{
    float ce = accums[0] / (float)BATCH;
    float cl = accums[1] / (2.0f * (float)BATCH);
    float sc = accums[2] / ((float)BATCH * (float)(BATCH - 1));
    out[0] = ce + cl + sc;
}

extern "C" void kernel_launch(void* const* d_in, const int* in_sizes, int n_in,
                              void* d_out, int out_size, void* d_ws, size_t ws_size,
                              hipStream_t stream)
{
    const float* feat    = (const float*)d_in[0];
    const int*   labels  = (const int*)d_in[1];
    const float* logits  = (const float*)d_in[2];
    const float* sim     = (const float*)d_in[3];
    const float* centers = (const float*)d_in[4];
    float* out = (float*)d_out;

    float* accums = (float*)d_ws;
    unsigned short* fn = (unsigned short*)((char*)d_ws + 256);

    hipMemsetAsync(d_ws, 0, 256, stream);
    prep_kernel<<<BATCH / 4, 256, 0, stream>>>(feat, labels, centers, accums, fn);
    ce_kernel<<<BATCH / 256, 256, 0, stream>>>(logits, labels, accums);
    soft_kernel<<<528, 512, 0, stream>>>(fn, labels, sim, accums);
    finalize_kernel<<<1, 1, 0, stream>>>(accums, out);
}

// Round 8
// 185.394 us; speedup vs baseline: 1.8890x; 1.2514x over previous
//
#include <hip/hip_runtime.h>
#include <hip/hip_bf16.h>
#include <stdint.h>

#define BATCH 8192
#define DDIM 1024
#define EPSN 1e-8f

typedef __bf16 bf16x8 __attribute__((ext_vector_type(8)));
typedef float f32x4 __attribute__((ext_vector_type(4)));

// ws layout:
//   +0     : part_cp[2048]   (prep center-loss partials, one per block)
//   +8192  : part_ce[32]     (ce partials)
//   +8320  : part_soft[528]  (soft-cosine partials)
//   +16384 : fn bf16 [8192][1024]  (16 MiB)
#define WS_CP   0
#define WS_CE   2048
#define WS_SOFT 2080
#define WS_FN   8192   // in floats (16384 bytes)

__device__ __forceinline__ unsigned short f2bf(float x) {
    unsigned int u = __builtin_bit_cast(unsigned int, x);
    unsigned int r = (u + 0x7fffu + ((u >> 16) & 1u)) >> 16;
    return (unsigned short)r;
}

__device__ __forceinline__ void gload16(const void* g, void* l) {
    __builtin_amdgcn_global_load_lds(
        (const __attribute__((address_space(1))) void*)g,
        (__attribute__((address_space(3))) void*)l, 16, 0, 0);
}

// ---------------- prep: row norms -> fn (bf16), center loss partials ----------
__global__ __launch_bounds__(256) void prep_kernel(
    const float* __restrict__ feat, const int* __restrict__ labels,
    const float* __restrict__ centers, float* __restrict__ part_cp,
    unsigned short* __restrict__ fn)
{
    __shared__ float pr[4];
    int wave = threadIdx.x >> 6;
    int lane = threadIdx.x & 63;
    int row  = blockIdx.x * 4 + wave;
    const float* frow = feat + (size_t)row * DDIM;
    int lab = labels[row];
    const float* crow = centers + (size_t)lab * DDIM;

    float4 f[4];
    float ss = 0.f, cp = 0.f;
#pragma unroll
    for (int q = 0; q < 4; q++) {
        f[q] = *(const float4*)(frow + q * 256 + lane * 4);
        float4 cv = *(const float4*)(crow + q * 256 + lane * 4);
        ss += f[q].x * f[q].x + f[q].y * f[q].y + f[q].z * f[q].z + f[q].w * f[q].w;
        float dx = f[q].x - cv.x, dy = f[q].y - cv.y, dz = f[q].z - cv.z, dw = f[q].w - cv.w;
        cp += dx * dx + dy * dy + dz * dz + dw * dw;
    }
#pragma unroll
    for (int o = 32; o > 0; o >>= 1) {
        ss += __shfl_xor(ss, o);
        cp += __shfl_xor(cp, o);
    }
    float scale = 1.0f / fmaxf(sqrtf(ss), EPSN);
#pragma unroll
    for (int q = 0; q < 4; q++) {
        ushort4 o4;
        o4.x = f2bf(f[q].x * scale);
        o4.y = f2bf(f[q].y * scale);
        o4.z = f2bf(f[q].z * scale);
        o4.w = f2bf(f[q].w * scale);
        *(ushort4*)(fn + (size_t)row * DDIM + q * 256 + lane * 4) = o4;
    }
    if (lane == 0) pr[wave] = cp;
    __syncthreads();
    if (threadIdx.x == 0) part_cp[blockIdx.x] = pr[0] + pr[1] + pr[2] + pr[3];
}

// ---------------- cross entropy ----------------
__global__ __launch_bounds__(256) void ce_kernel(
    const float* __restrict__ logits, const int* __restrict__ labels,
    float* __restrict__ part_ce)
{
    __shared__ float pr[4];
    int i = blockIdx.x * 256 + threadIdx.x;
    float4 a = *(const float4*)(logits + (size_t)i * 8);
    float4 b = *(const float4*)(logits + (size_t)i * 8 + 4);
    float lv[8] = {a.x, a.y, a.z, a.w, b.x, b.y, b.z, b.w};
    int lab = labels[i];
    float m = lv[0];
#pragma unroll
    for (int k = 1; k < 8; k++) m = fmaxf(m, lv[k]);
    float s = 0.f, tgt = 0.f;
#pragma unroll
    for (int k = 0; k < 8; k++) {
        s += __expf(lv[k] - m);
        tgt += (k == lab) ? lv[k] : 0.f;
    }
    float ce = (m + __logf(s)) - tgt;
#pragma unroll
    for (int o = 32; o > 0; o >>= 1) ce += __shfl_xor(ce, o);
    if ((threadIdx.x & 63) == 0) pr[threadIdx.x >> 6] = ce;
    __syncthreads();
    if (threadIdx.x == 0) part_ce[blockIdx.x] = pr[0] + pr[1] + pr[2] + pr[3];
}

// ---------------- soft-cosine: 256^2 tile, M-split 8-phase schedule ----------
// Regions: s&3 = 0:Akk0 1:Bkk0 2:Akk1 3:Bkk1, each [256][32] bf16 (16KB, 2 gloads/thread).
// Phase q consumes region pair {q&~1, q|1}; ISSUE(q+5) (ring 8 slots, distance 5).
// vmcnt counts LOADS (2 per region). Odd-phase vmcnt(6) = 3 regions outstanding
// => regions <= q+2 landed, covering the next two phases' pairs. Single barrier
// per phase; distance-5 slot reuse is >= 2 barriers after last reader.
// M-split: PH0 reads a[0..3]+b[0..3] (8 ds_read_b128, 16 MFMA), PH1 reads
// a[4..7] only (4 reads, 16 MFMA, b reused in regs) -> balanced lgkm pressure.
// LDS XOR-swizzle: chunk16 ^ ((row>>1)&3) on both staging source and ds_read.

__global__ __launch_bounds__(512, 2) void soft_kernel(
    const unsigned short* __restrict__ fn, const int* __restrict__ labels,
    const float* __restrict__ sim, float* __restrict__ part_soft)
{
    __shared__ __align__(16) unsigned short tiles[2][4][256][32];  // 128 KiB
    __shared__ int lrow[256], lcol[256];
    __shared__ float Ssm[64], W2s[64];
    __shared__ float red[8];

    int tid  = threadIdx.x;
    int lane = tid & 63;
    int w    = tid >> 6;
    int wr   = w >> 2, wc = w & 3;      // 2x4 wave grid; wave owns 128x64
    int lr16 = lane & 15;
    int kgrp = lane >> 4;

    // triangle decode with bijective XCD swizzle (528 = 8*66)
    int b0i = blockIdx.x;
    int swz = (b0i & 7) * 66 + (b0i >> 3);
    int tr = 0, rem = swz;
    while (rem >= 32 - tr) { rem -= 32 - tr; tr++; }
    int tc = tr + rem;
    bool diag = (tr == tc);

    const unsigned short* Abase = fn + (size_t)tr * 256 * DDIM;
    const unsigned short* Bbase = fn + (size_t)tc * 256 * DDIM;

    // staging geometry: region = 1024 slots of 16B; thread covers idx = {tid, 512+tid}
    int myrow  = tid >> 2;                     // 0..127 (second load adds 128)
    int mychk  = tid & 3;
    int mycol8 = mychk ^ ((myrow >> 1) & 3);   // pre-swizzled global source
    int goff0  = myrow * DDIM + mycol8 * 8;

    auto ISSUE = [&](int s) {
        int kt_s = s >> 2, r = s & 3, kk = r >> 1;
        const unsigned short* gb = (r & 1) ? Bbase : Abase;
        const unsigned short* g0 = gb + goff0 + kt_s * 64 + kk * 32;
        unsigned short* l0 = &tiles[kt_s & 1][r][0][0] + tid * 8;
        gload16(g0, l0);
        gload16(g0 + 128 * DDIM, l0 + 512 * 8);
    };

    // prologue: stage regions 0..4 (10 loads), labels/weights, wait regions {0,1}
#pragma unroll
    for (int s = 0; s < 5; s++) ISSUE(s);
    if (tid < 256) {
        lrow[tid] = labels[tr * 256 + tid];
        lcol[tid] = labels[tc * 256 + tid];
    }
    if (tid < 64) {
        float sv = sim[tid];
        Ssm[tid] = sv;
        W2s[tid] = sv + sim[(tid & 7) * 8 + (tid >> 3)];
    }
    asm volatile("s_waitcnt vmcnt(6) lgkmcnt(0)" ::: "memory");
    __builtin_amdgcn_s_barrier();
    asm volatile("" ::: "memory");

    f32x4 acc[8][4] = {};
    bf16x8 av[4], bv[4];

#define VMW(N) asm volatile("s_waitcnt vmcnt(" #N ")" ::: "memory");
#define NOVM

#define PH0(BUF, KK, S, WAIT) { \
    if ((S) <= 63) ISSUE(S); \
    const unsigned short* Ar = &tiles[BUF][(KK)*2][0][0]; \
    const unsigned short* Br = &tiles[BUF][(KK)*2+1][0][0]; \
    _Pragma("unroll") \
    for (int j = 0; j < 4; j++) { \
        int row = wr * 128 + j * 16 + lr16; \
        av[j] = *(const bf16x8*)((const char*)Ar + row * 64 + ((kgrp ^ ((row >> 1) & 3)) * 16)); \
        int col = wc * 64 + j * 16 + lr16; \
        bv[j] = *(const bf16x8*)((const char*)Br + col * 64 + ((kgrp ^ ((col >> 1) & 3)) * 16)); \
    } \
    WAIT \
    __builtin_amdgcn_s_barrier(); \
    asm volatile("" ::: "memory"); \
    __builtin_amdgcn_s_setprio(1); \
    _Pragma("unroll") \
    for (int j = 0; j < 4; j++) \
        _Pragma("unroll") \
        for (int n = 0; n < 4; n++) \
            acc[j][n] = __builtin_amdgcn_mfma_f32_16x16x32_bf16(av[j], bv[n], acc[j][n], 0, 0, 0); \
    __builtin_amdgcn_s_setprio(0); \
}

#define PH1(BUF, KK, S, WAIT) { \
    if ((S) <= 63) ISSUE(S); \
    const unsigned short* Ar = &tiles[BUF][(KK)*2][0][0]; \
    _Pragma("unroll") \
    for (int j = 0; j < 4; j++) { \
        int row = wr * 128 + 64 + j * 16 + lr16; \
        av[j] = *(const bf16x8*)((const char*)Ar + row * 64 + ((kgrp ^ ((row >> 1) & 3)) * 16)); \
    } \
    WAIT \
    __builtin_amdgcn_s_barrier(); \
    asm volatile("" ::: "memory"); \
    __builtin_amdgcn_s_setprio(1); \
    _Pragma("unroll") \
    for (int j = 0; j < 4; j++) \
        _Pragma("unroll") \
        for (int n = 0; n < 4; n++) \
            acc[4 + j][n] = __builtin_amdgcn_mfma_f32_16x16x32_bf16(av[j], bv[n], acc[4 + j][n], 0, 0, 0); \
    __builtin_amdgcn_s_setprio(0); \
}

#define KTILE(BUF, QB, W1, W3) \
    PH0(BUF, 0, (QB) + 5, NOVM) \
    PH1(BUF, 0, (QB) + 6, W1) \
    PH0(BUF, 1, (QB) + 7, NOVM) \
    PH1(BUF, 1, (QB) + 8, W3)

    int q = 0;
    for (int i = 0; i < 7; i++) {          // kt = 0..13
        KTILE(0, q, VMW(6), VMW(6)) q += 4;
        KTILE(1, q, VMW(6), VMW(6)) q += 4;
    }
    KTILE(0, 56, VMW(6), VMW(4))            // kt = 14 (phases 56-59)
    KTILE(1, 60, VMW(0), NOVM)              // kt = 15 (phases 60-63)

#undef KTILE
#undef PH0
#undef PH1
#undef VMW
#undef NOVM

    // epilogue: sum w_ij * relu(1 - cos) over this 256x256 tile
    float local = 0.f;
    int lb[4], cc[4];
#pragma unroll
    for (int n = 0; n < 4; n++) { cc[n] = wc * 64 + n * 16 + lr16; lb[n] = lcol[cc[n]]; }
#pragma unroll
    for (int m = 0; m < 8; m++) {
#pragma unroll
        for (int rg = 0; rg < 4; rg++) {
            int r = wr * 128 + m * 16 + kgrp * 4 + rg;
            int la8 = lrow[r] * 8;
#pragma unroll
            for (int n = 0; n < 4; n++) {
                float v = fmaxf(1.0f - acc[m][n][rg], 0.f);
                float wgt = diag ? ((r == cc[n]) ? 0.f : Ssm[la8 + lb[n]])
                                 : W2s[la8 + lb[n]];
                local += wgt * v;
            }
        }
    }
#pragma unroll
    for (int o = 32; o > 0; o >>= 1) local += __shfl_xor(local, o);
    if (lane == 0) red[w] = local;
    __syncthreads();
    if (tid == 0) {
        float s = 0.f;
#pragma unroll
        for (int k = 0; k < 8; k++) s += red[k];
        part_soft[blockIdx.x] = s;
    }
}

// ---------------- finalize: reduce all partials ----------------
__global__ __launch_bounds__(512) void finalize_kernel(
    const float* __restrict__ ws, float* __restrict__ out)
{
    __shared__ float red[8];
    int tid = threadIdx.x;
    const float invB  = 1.0f / (float)BATCH;
    const float inv2B = 0.5f / (float)BATCH;
    const float invBB = 1.0f / ((float)BATCH * (float)(BATCH - 1));

    float local = 0.f;
    for (int i = tid; i < 2048; i += 512) local += ws[WS_CP + i] * inv2B;
    if (tid < 32)  local += ws[WS_CE + tid] * invB;
    local += ws[WS_SOFT + tid] * invBB;            // tid 0..511
    if (tid < 16) local += ws[WS_SOFT + 512 + tid] * invBB;  // tail 512..527

#pragma unroll
    for (int o = 32; o > 0; o >>= 1) local += __shfl_xor(local, o);
    if ((tid & 63) == 0) red[tid >> 6] = local;
    __syncthreads();
    if (tid == 0) {
        float s = 0.f;
#pragma unroll
        for (int k = 0; k < 8; k++) s += red[k];
        out[0] = s;
    }
}

extern "C" void kernel_launch(void* const* d_in, const int* in_sizes, int n_in,
                              void* d_out, int out_size, void* d_ws, size_t ws_size,
                              hipStream_t stream)
{
    const float* feat    = (const float*)d_in[0];
    const int*   labels  = (const int*)d_in[1];
    const float* logits  = (const float*)d_in[2];
    const float* sim     = (const float*)d_in[3];
    const float* centers = (const float*)d_in[4];
    float* out = (float*)d_out;

    float* ws = (float*)d_ws;
    unsigned short* fn = (unsigned short*)((char*)d_ws + WS_FN * 4);

    prep_kernel<<<BATCH / 4, 256, 0, stream>>>(feat, labels, centers, ws + WS_CP, fn);
    ce_kernel<<<BATCH / 256, 256, 0, stream>>>(logits, labels, ws + WS_CE);
    soft_kernel<<<528, 512, 0, stream>>>(fn, labels, sim, ws + WS_SOFT);
    finalize_kernel<<<1, 512, 0, stream>>>(ws, out);
}